// Round 1
// baseline (343.070 us; speedup 1.0000x reference)
//
#include <hip/hip_runtime.h>

typedef __bf16 bf16x8 __attribute__((ext_vector_type(8)));
typedef float  f32x4  __attribute__((ext_vector_type(4)));

#define BM    64
#define DDEC  176
#define DSP   54
#define K1    222
#define K1P   224
#define HID   256
#define XSTR  232   // padded x row stride (bf16 elems): 464B -> 2-way LDS conflict
#define HSTR  264   // padded h row stride: 528B -> 2-way LDS conflict

#define WT1_OFF 57344           // 256*224
#define WT2_OFF 122880          // + 256*256
#define MLP_WS  131072          // + 32*256  (bf16 elems per MLP)

// DQ_IN joint order: [0,3,6,9,12,13,14,15,16,17,18,19,20,21] extended by the
// parent chain 21->19->17->14->9->6->3->0
__constant__ int c_nodes[21] = {0,3,6,9,12,13,14,15,16,17,18,19,20,21,19,17,14,9,6,3,0};

struct Biases {
  const float* b0[3];
  const float* b1[3];
  const float* b2[3];
};

// ---- convert/transpose weights to bf16: Wt0[256][224], Wt1[256][256], Wt2[32][256] per MLP
__global__ __launch_bounds__(256) void prep_weights(
    const float* __restrict__ w0a, const float* __restrict__ w1a, const float* __restrict__ w2a,
    const float* __restrict__ w0b, const float* __restrict__ w1b, const float* __restrict__ w2b,
    const float* __restrict__ w0c, const float* __restrict__ w1c, const float* __restrict__ w2c,
    __bf16* __restrict__ ws)
{
  int idx = blockIdx.x * 256 + threadIdx.x;
  if (idx >= 3 * MLP_WS) return;
  int m = idx / MLP_WS;
  int r = idx - m * MLP_WS;
  const float* w0 = (m == 0) ? w0a : (m == 1) ? w0b : w0c;
  const float* w1 = (m == 0) ? w1a : (m == 1) ? w1b : w1c;
  const float* w2 = (m == 0) ? w2a : (m == 1) ? w2b : w2c;
  float v;
  if (r < WT1_OFF) {                 // Wt0[n][k] = w0[k][n], k padded to 224
    int n = r / K1P;
    int k = r - n * K1P;
    v = (k < K1) ? w0[k * HID + n] : 0.0f;
  } else if (r < WT2_OFF) {          // Wt1[n][k] = w1[k][n]
    int rr = r - WT1_OFF;
    int n = rr >> 8, k = rr & 255;
    v = w1[k * HID + n];
  } else {                           // Wt2[n][k] = w2[k][n], n padded to 32
    int rr = r - WT2_OFF;
    int n = rr >> 8, k = rr & 255;
    int od = (m == 0) ? 8 : 24;
    v = (n < od) ? w2[k * od + n] : 0.0f;
  }
  ws[idx] = (__bf16)v;
}

__global__ __launch_bounds__(256) void trunk_fused(
    const float* __restrict__ sparse, const float* __restrict__ dec,
    const __bf16* __restrict__ ws, float* __restrict__ out,
    Biases bp, int nrows)
{
  __shared__ __align__(16) __bf16 xls[BM * XSTR];
  __shared__ __align__(16) __bf16 hls[BM * HSTR];

  const int tid  = threadIdx.x;
  const int lane = tid & 63;
  const int wid  = tid >> 6;            // 4 waves
  const int lr   = lane & 15;           // A-row / B-col / C-col
  const int lk   = (lane >> 4) << 3;    // k sub-offset (8 elems per lane group)
  const int lrow = (lane >> 4) << 2;    // C-row base
  const long row0 = (long)blockIdx.x * BM;

  // ---- phase 0: gather x (dec[DQ_IN] ++ sparse) -> LDS bf16, zero-pad to 224
  for (int e = tid; e < BM * K1P; e += 256) {
    int r = e / K1P;
    int i = e - r * K1P;
    long grow = row0 + r;
    float v = 0.0f;
    if (grow < nrows) {
      if (i < 168)       v = dec[grow * DDEC + c_nodes[i >> 3] * 8 + (i & 7)];
      else if (i < K1)   v = sparse[grow * DSP + (i - 168)];
    }
    xls[r * XSTR + i] = (__bf16)v;
  }
  __syncthreads();

  for (int m = 0; m < 3; ++m) {
    const __bf16* wt0 = ws + m * MLP_WS;
    const __bf16* wt1 = wt0 + WT1_OFF;
    const __bf16* wt2 = wt0 + WT2_OFF;
    const float* b0 = bp.b0[m];
    const float* b1 = bp.b1[m];
    const float* b2 = bp.b2[m];
    const int nc0 = wid << 6;  // wave's 64-col slice of the 256 hidden cols

    // ---- layer 0: h1 = lrelu(x @ W0 + b0)   (K = 224)
    {
      f32x4 acc[4][4] = {};
      #pragma unroll
      for (int kk = 0; kk < K1P / 32; ++kk) {
        const int kof = kk * 32 + lk;
        bf16x8 af[4], bfr[4];
        #pragma unroll
        for (int mi = 0; mi < 4; ++mi)
          af[mi] = *(const bf16x8*)&xls[(mi * 16 + lr) * XSTR + kof];
        #pragma unroll
        for (int ni = 0; ni < 4; ++ni)
          bfr[ni] = *(const bf16x8*)&wt0[(size_t)(nc0 + ni * 16 + lr) * K1P + kof];
        #pragma unroll
        for (int mi = 0; mi < 4; ++mi)
          #pragma unroll
          for (int ni = 0; ni < 4; ++ni)
            acc[mi][ni] = __builtin_amdgcn_mfma_f32_16x16x32_bf16(af[mi], bfr[ni], acc[mi][ni], 0, 0, 0);
      }
      // epilogue: bias + leaky relu -> hls (hls free: prev reads fenced by loop-end barrier)
      #pragma unroll
      for (int ni = 0; ni < 4; ++ni) {
        const int col = nc0 + ni * 16 + lr;
        const float bv = b0[col];
        #pragma unroll
        for (int mi = 0; mi < 4; ++mi)
          #pragma unroll
          for (int i = 0; i < 4; ++i) {
            float v = acc[mi][ni][i] + bv;
            v = (v > 0.0f) ? v : 0.01f * v;
            hls[(mi * 16 + lrow + i) * HSTR + col] = (__bf16)v;
          }
      }
      __syncthreads();
    }

    // ---- layer 1: h2 = lrelu(h1 @ W1 + b1)  (K = 256), h2 overwrites h1
    {
      f32x4 acc[4][4] = {};
      #pragma unroll
      for (int kk = 0; kk < 8; ++kk) {
        const int kof = kk * 32 + lk;
        bf16x8 af[4], bfr[4];
        #pragma unroll
        for (int mi = 0; mi < 4; ++mi)
          af[mi] = *(const bf16x8*)&hls[(mi * 16 + lr) * HSTR + kof];
        #pragma unroll
        for (int ni = 0; ni < 4; ++ni)
          bfr[ni] = *(const bf16x8*)&wt1[(size_t)(nc0 + ni * 16 + lr) * HID + kof];
        #pragma unroll
        for (int mi = 0; mi < 4; ++mi)
          #pragma unroll
          for (int ni = 0; ni < 4; ++ni)
            acc[mi][ni] = __builtin_amdgcn_mfma_f32_16x16x32_bf16(af[mi], bfr[ni], acc[mi][ni], 0, 0, 0);
      }
      __syncthreads();  // ALL waves done reading h1 before overwrite
      #pragma unroll
      for (int ni = 0; ni < 4; ++ni) {
        const int col = nc0 + ni * 16 + lr;
        const float bv = b1[col];
        #pragma unroll
        for (int mi = 0; mi < 4; ++mi)
          #pragma unroll
          for (int i = 0; i < 4; ++i) {
            float v = acc[mi][ni][i] + bv;
            v = (v > 0.0f) ? v : 0.01f * v;
            hls[(mi * 16 + lrow + i) * HSTR + col] = (__bf16)v;
          }
      }
      __syncthreads();
    }

    // ---- layer 2: res = h2 @ W2 + b2  (out padded to 32 cols; wave owns 16 rows)
    {
      f32x4 acc2[2] = {};
      const int mr0 = wid << 4;
      #pragma unroll
      for (int kk = 0; kk < 8; ++kk) {
        const int kof = kk * 32 + lk;
        bf16x8 af  = *(const bf16x8*)&hls[(mr0 + lr) * HSTR + kof];
        bf16x8 bw0 = *(const bf16x8*)&wt2[(size_t)(lr) * HID + kof];
        bf16x8 bw1 = *(const bf16x8*)&wt2[(size_t)(16 + lr) * HID + kof];
        acc2[0] = __builtin_amdgcn_mfma_f32_16x16x32_bf16(af, bw0, acc2[0], 0, 0, 0);
        acc2[1] = __builtin_amdgcn_mfma_f32_16x16x32_bf16(af, bw1, acc2[1], 0, 0, 0);
      }
      // scatter res back into x (MLP 0/1) or store final result (MLP 2)
      #pragma unroll
      for (int ni = 0; ni < 2; ++ni) {
        const int col = ni * 16 + lr;
        #pragma unroll
        for (int i = 0; i < 4; ++i) {
          const int row = mr0 + lrow + i;
          float v = acc2[ni][i];
          if (m == 2) {
            if (col < 24) {
              long grow = row0 + row;
              if (grow < nrows) out[grow * 24 + col] = v + b2[col];
            }
          } else if (m == 0) {
            if (col < 8) {  // joint 9 at node positions 3 and 17
              __bf16 bb = (__bf16)(v + b2[col]);
              xls[row * XSTR + 24  + col] = bb;
              xls[row * XSTR + 136 + col] = bb;
            }
          } else {
            if (col < 24) {  // joints 6 (pos 2,18), 9 (pos 3,17), 12 (pos 4)
              __bf16 bb = (__bf16)(v + b2[col]);
              if (col < 8)       { xls[row * XSTR + 16 + col]        = bb;
                                   xls[row * XSTR + 144 + col]       = bb; }
              else if (col < 16) { xls[row * XSTR + 24 + (col - 8)]  = bb;
                                   xls[row * XSTR + 136 + (col - 8)] = bb; }
              else               { xls[row * XSTR + 32 + (col - 16)] = bb; }
            }
          }
        }
      }
      __syncthreads();
    }
  }
}

extern "C" void kernel_launch(void* const* d_in, const int* in_sizes, int n_in,
                              void* d_out, int out_size, void* d_ws, size_t ws_size,
                              hipStream_t stream)
{
  const float* sparse = (const float*)d_in[0];
  const float* dec    = (const float*)d_in[1];
  Biases bp;
  const float* w0[3]; const float* w1[3]; const float* w2[3];
  for (int m = 0; m < 3; ++m) {
    w0[m]    = (const float*)d_in[2 + m * 6 + 0];
    bp.b0[m] = (const float*)d_in[2 + m * 6 + 1];
    w1[m]    = (const float*)d_in[2 + m * 6 + 2];
    bp.b1[m] = (const float*)d_in[2 + m * 6 + 3];
    w2[m]    = (const float*)d_in[2 + m * 6 + 4];
    bp.b2[m] = (const float*)d_in[2 + m * 6 + 5];
  }
  __bf16* ws = (__bf16*)d_ws;
  const int nrows = in_sizes[0] / DSP;   // 131072

  const int prep_total = 3 * MLP_WS;
  prep_weights<<<(prep_total + 255) / 256, 256, 0, stream>>>(
      w0[0], w1[0], w2[0], w0[1], w1[1], w2[1], w0[2], w1[2], w2[2], ws);

  const int nblocks = (nrows + BM - 1) / BM;
  trunk_fused<<<nblocks, 256, 0, stream>>>(sparse, dec, ws, (float*)d_out, bp, nrows);
}

// Round 2
// 258.281 us; speedup vs baseline: 1.3283x; 1.3283x over previous
//
#include <hip/hip_runtime.h>

typedef __bf16 bf16x8 __attribute__((ext_vector_type(8)));
typedef __bf16 bf16x4 __attribute__((ext_vector_type(4)));
typedef float  f32x4  __attribute__((ext_vector_type(4)));

#define BM    64
#define DDEC  176
#define DSP   54
#define K1    222
#define K1P   224
#define HID   256
#define XSTR  232   // padded x row stride (bf16): 464B -> 2-way LDS conflict (free)
#define HSTR  264   // padded h row stride: 528B

#define WT1_OFF 57344           // 256*224
#define WT2_OFF 122880          // + 256*256
#define MLP_WS  131072          // + 32*256  (bf16 elems per MLP)

// DQ_IN joint order: [0,3,6,9,12,13,14,15,16,17,18,19,20,21] + parent chain 21->...->0
__constant__ int c_nodes[21] = {0,3,6,9,12,13,14,15,16,17,18,19,20,21,19,17,14,9,6,3,0};

struct Biases {
  const float* b1[3];
  const float* b2[3];
};

// ---- convert/transpose weights to bf16: Wt0[256][224] (b0 folded at k=222),
// Wt1[256][256], Wt2[32][256] per MLP
__global__ __launch_bounds__(256) void prep_weights(
    const float* __restrict__ w0a, const float* __restrict__ w1a, const float* __restrict__ w2a,
    const float* __restrict__ w0b, const float* __restrict__ w1b, const float* __restrict__ w2b,
    const float* __restrict__ w0c, const float* __restrict__ w1c, const float* __restrict__ w2c,
    const float* __restrict__ b0a, const float* __restrict__ b0b, const float* __restrict__ b0c,
    __bf16* __restrict__ ws)
{
  int idx = blockIdx.x * 256 + threadIdx.x;
  if (idx >= 3 * MLP_WS) return;
  int m = idx / MLP_WS;
  int r = idx - m * MLP_WS;
  const float* w0 = (m == 0) ? w0a : (m == 1) ? w0b : w0c;
  const float* w1 = (m == 0) ? w1a : (m == 1) ? w1b : w1c;
  const float* w2 = (m == 0) ? w2a : (m == 1) ? w2b : w2c;
  const float* b0 = (m == 0) ? b0a : (m == 1) ? b0b : b0c;
  float v;
  if (r < WT1_OFF) {                 // Wt0[n][k] = w0[k][n]; k=222 -> b0[n]; k=223 -> 0
    int n = r / K1P;
    int k = r - n * K1P;
    v = (k < K1) ? w0[k * HID + n] : (k == K1 ? b0[n] : 0.0f);
  } else if (r < WT2_OFF) {          // Wt1[n][k] = w1[k][n]
    int rr = r - WT1_OFF;
    int n = rr >> 8, k = rr & 255;
    v = w1[k * HID + n];
  } else {                           // Wt2[n][k] = w2[k][n], n padded to 32
    int rr = r - WT2_OFF;
    int n = rr >> 8, k = rr & 255;
    int od = (m == 0) ? 8 : 24;
    v = (n < od) ? w2[k * od + n] : 0.0f;
  }
  ws[idx] = (__bf16)v;
}

__global__ __launch_bounds__(512, 4) void trunk_fused(
    const float* __restrict__ sparse, const float* __restrict__ dec,
    const __bf16* __restrict__ ws, float* __restrict__ out,
    Biases bp, int nrows)
{
  __shared__ __align__(16) __bf16 xls[BM * XSTR];
  __shared__ __align__(16) __bf16 hls[BM * HSTR];

  const int tid  = threadIdx.x;
  const int lane = tid & 63;
  const int wid  = tid >> 6;            // 8 waves
  const int lr   = lane & 15;           // A-row / B-col / C-col
  const int lk   = (lane >> 4) << 3;    // k sub-offset (8 elems per lane group)
  const int lrow = (lane >> 4) << 2;    // C-row base
  const long row0 = (long)blockIdx.x * BM;

  // ---- phase 0: vectorized gather x = (dec[DQ_IN] ++ sparse ++ [1,0]) -> LDS bf16
  // 56 float4-slots per row: slots 0..41 from dec (per-joint 8-float runs),
  // 42..54 from sparse (float2 pairs), 55 = sparse[52],sparse[53],1.0,0.0
  for (int s = tid; s < BM * 56; s += 512) {
    int r = s / 56;
    int q = s - r * 56;
    long grow = row0 + r;
    float4 v = make_float4(0.f, 0.f, 0.f, 0.f);
    if (grow < nrows) {
      if (q < 42) {
        const float* p = dec + grow * DDEC + c_nodes[q >> 1] * 8 + (q & 1) * 4;
        v = *(const float4*)p;
      } else if (q < 55) {
        const float* p = sparse + grow * DSP + (q * 4 - 168);
        float2 a = *(const float2*)p;
        float2 b = *(const float2*)(p + 2);
        v = make_float4(a.x, a.y, b.x, b.y);
      } else {
        const float* p = sparse + grow * DSP + 52;
        float2 a = *(const float2*)p;
        v = make_float4(a.x, a.y, 1.0f, 0.0f);
      }
    } else if (q == 55) {
      v = make_float4(0.f, 0.f, 1.0f, 0.f);
    }
    bf16x4 bb = { (__bf16)v.x, (__bf16)v.y, (__bf16)v.z, (__bf16)v.w };
    *(bf16x4*)&xls[r * XSTR + q * 4] = bb;
  }
  __syncthreads();

  for (int m = 0; m < 3; ++m) {
    const __bf16* wt0 = ws + m * MLP_WS;
    const __bf16* wt1 = wt0 + WT1_OFF;
    const __bf16* wt2 = wt0 + WT2_OFF;
    const float* b1 = bp.b1[m];
    const float* b2 = bp.b2[m];
    const int nc0 = wid << 5;  // wave's 32-col slice of the 256 hidden cols

    // ---- layer 0: h1 = lrelu(x @ W0)   (K = 224, bias folded at k=222)
    {
      f32x4 acc[4][2] = {};
      #pragma unroll
      for (int kk = 0; kk < K1P / 32; ++kk) {
        const int kof = kk * 32 + lk;
        bf16x8 af[4], bfr[2];
        #pragma unroll
        for (int mi = 0; mi < 4; ++mi)
          af[mi] = *(const bf16x8*)&xls[(mi * 16 + lr) * XSTR + kof];
        #pragma unroll
        for (int ni = 0; ni < 2; ++ni)
          bfr[ni] = *(const bf16x8*)&wt0[(size_t)(nc0 + ni * 16 + lr) * K1P + kof];
        #pragma unroll
        for (int mi = 0; mi < 4; ++mi)
          #pragma unroll
          for (int ni = 0; ni < 2; ++ni)
            acc[mi][ni] = __builtin_amdgcn_mfma_f32_16x16x32_bf16(af[mi], bfr[ni], acc[mi][ni], 0, 0, 0);
      }
      #pragma unroll
      for (int ni = 0; ni < 2; ++ni) {
        const int col = nc0 + ni * 16 + lr;
        #pragma unroll
        for (int mi = 0; mi < 4; ++mi)
          #pragma unroll
          for (int i = 0; i < 4; ++i) {
            float v = acc[mi][ni][i];
            v = (v > 0.0f) ? v : 0.01f * v;
            hls[(mi * 16 + lrow + i) * HSTR + col] = (__bf16)v;
          }
      }
      __syncthreads();
    }

    // ---- layer 1: h2 = lrelu(h1 @ W1 + b1)  (K = 256), h2 overwrites h1
    {
      f32x4 acc[4][2] = {};
      #pragma unroll
      for (int kk = 0; kk < 8; ++kk) {
        const int kof = kk * 32 + lk;
        bf16x8 af[4], bfr[2];
        #pragma unroll
        for (int mi = 0; mi < 4; ++mi)
          af[mi] = *(const bf16x8*)&hls[(mi * 16 + lr) * HSTR + kof];
        #pragma unroll
        for (int ni = 0; ni < 2; ++ni)
          bfr[ni] = *(const bf16x8*)&wt1[(size_t)(nc0 + ni * 16 + lr) * HID + kof];
        #pragma unroll
        for (int mi = 0; mi < 4; ++mi)
          #pragma unroll
          for (int ni = 0; ni < 2; ++ni)
            acc[mi][ni] = __builtin_amdgcn_mfma_f32_16x16x32_bf16(af[mi], bfr[ni], acc[mi][ni], 0, 0, 0);
      }
      __syncthreads();  // ALL waves done reading h1 before overwrite
      #pragma unroll
      for (int ni = 0; ni < 2; ++ni) {
        const int col = nc0 + ni * 16 + lr;
        const float bv = b1[col];
        #pragma unroll
        for (int mi = 0; mi < 4; ++mi)
          #pragma unroll
          for (int i = 0; i < 4; ++i) {
            float v = acc[mi][ni][i] + bv;
            v = (v > 0.0f) ? v : 0.01f * v;
            hls[(mi * 16 + lrow + i) * HSTR + col] = (__bf16)v;
          }
      }
      __syncthreads();
    }

    // ---- layer 2: res = h2 @ W2 + b2  (out padded to 32 cols)
    // wave w: row-frag (w>>1), col-frag (w&1)  -> one 16x16 output frag per wave
    {
      f32x4 acc2 = {};
      const int mr0 = (wid >> 1) << 4;
      const int ni  = wid & 1;
      #pragma unroll
      for (int kk = 0; kk < 8; ++kk) {
        const int kof = kk * 32 + lk;
        bf16x8 af = *(const bf16x8*)&hls[(mr0 + lr) * HSTR + kof];
        bf16x8 bw = *(const bf16x8*)&wt2[(size_t)(ni * 16 + lr) * HID + kof];
        acc2 = __builtin_amdgcn_mfma_f32_16x16x32_bf16(af, bw, acc2, 0, 0, 0);
      }
      const int col = ni * 16 + lr;
      #pragma unroll
      for (int i = 0; i < 4; ++i) {
        const int row = mr0 + lrow + i;
        float v = acc2[i];
        if (m == 2) {
          if (col < 24) {
            long grow = row0 + row;
            if (grow < nrows) out[grow * 24 + col] = v + b2[col];
          }
        } else if (m == 0) {
          if (col < 8) {  // joint 9 at node positions 3 and 17
            __bf16 bb = (__bf16)(v + b2[col]);
            xls[row * XSTR + 24  + col] = bb;
            xls[row * XSTR + 136 + col] = bb;
          }
        } else {
          if (col < 24) {  // joints 6 (pos 2,18), 9 (pos 3,17), 12 (pos 4)
            __bf16 bb = (__bf16)(v + b2[col]);
            if (col < 8)       { xls[row * XSTR + 16 + col]        = bb;
                                 xls[row * XSTR + 144 + col]       = bb; }
            else if (col < 16) { xls[row * XSTR + 24 + (col - 8)]  = bb;
                                 xls[row * XSTR + 136 + (col - 8)] = bb; }
            else               { xls[row * XSTR + 32 + (col - 16)] = bb; }
          }
        }
      }
      if (m < 2) __syncthreads();
    }
  }
}

extern "C" void kernel_launch(void* const* d_in, const int* in_sizes, int n_in,
                              void* d_out, int out_size, void* d_ws, size_t ws_size,
                              hipStream_t stream)
{
  const float* sparse = (const float*)d_in[0];
  const float* dec    = (const float*)d_in[1];
  Biases bp;
  const float* w0[3]; const float* w1[3]; const float* w2[3]; const float* b0[3];
  for (int m = 0; m < 3; ++m) {
    w0[m]    = (const float*)d_in[2 + m * 6 + 0];
    b0[m]    = (const float*)d_in[2 + m * 6 + 1];
    w1[m]    = (const float*)d_in[2 + m * 6 + 2];
    bp.b1[m] = (const float*)d_in[2 + m * 6 + 3];
    w2[m]    = (const float*)d_in[2 + m * 6 + 4];
    bp.b2[m] = (const float*)d_in[2 + m * 6 + 5];
  }
  __bf16* ws = (__bf16*)d_ws;
  const int nrows = in_sizes[0] / DSP;   // 131072

  const int prep_total = 3 * MLP_WS;
  prep_weights<<<(prep_total + 255) / 256, 256, 0, stream>>>(
      w0[0], w1[0], w2[0], w0[1], w1[1], w2[1], w0[2], w1[2], w2[2],
      b0[0], b0[1], b0[2], ws);

  const int nblocks = (nrows + BM - 1) / BM;
  trunk_fused<<<nblocks, 512, 0, stream>>>(sparse, dec, ws, (float*)d_out, bp, nrows);
}